// Round 3
// baseline (542.096 us; speedup 1.0000x reference)
//
#include <hip/hip_runtime.h>
#include <hip/hip_bf16.h>
#include <stdint.h>

typedef __attribute__((ext_vector_type(8))) short short8;
typedef __attribute__((ext_vector_type(4))) float f32x4;
typedef __attribute__((ext_vector_type(4))) float float4v;
typedef __attribute__((ext_vector_type(4))) unsigned short ushort4v;

static constexpr int C = 512;
static constexpr int F = 2048;       // = N = K
static constexpr int NW = C * C;     // 262144 elements per weight

// RNE float -> bf16 bits (finite inputs)
__device__ inline unsigned short f2bf(float f) {
    union { float f; unsigned int u; } cv;
    cv.f = f;
    unsigned int r = cv.u + 0x7fffu + ((cv.u >> 16) & 1u);
    return (unsigned short)(r >> 16);
}

// ---------------- Kernel 1: per-weight sum(|w|), sum(w) in double ----------------
__global__ void qb_sums(const float* __restrict__ w0, const float* __restrict__ w1,
                        const float* __restrict__ w2, const float* __restrict__ w3,
                        double* __restrict__ sums) {
    int wid = blockIdx.x >> 6;       // 4 weights x 64 chunks
    int chunk = blockIdx.x & 63;
    const float* wsel = (wid == 0) ? w0 : (wid == 1) ? w1 : (wid == 2) ? w2 : w3;
    const float* p = wsel + chunk * (NW / 64);      // 4096 floats per chunk
    double sa = 0.0, sv = 0.0;
    for (int i = threadIdx.x; i < (NW / 64) / 4; i += 256) {
        float4v v = ((const float4v*)p)[i];
        sa += (double)fabsf(v.x) + fabsf(v.y) + fabsf(v.z) + fabsf(v.w);
        sv += (double)v.x + v.y + v.z + v.w;
    }
    for (int off = 32; off; off >>= 1) {
        sa += __shfl_down(sa, off);
        sv += __shfl_down(sv, off);
    }
    __shared__ double red[8];
    int wv = threadIdx.x >> 6;
    if ((threadIdx.x & 63) == 0) { red[wv] = sa; red[4 + wv] = sv; }
    __syncthreads();
    if (threadIdx.x == 0) {
        double tsa = red[0] + red[1] + red[2] + red[3];
        double tsv = red[4] + red[5] + red[6] + red[7];
        atomicAdd(&sums[wid * 2 + 0], tsa);
        atomicAdd(&sums[wid * 2 + 1], tsv);
    }
}

// ---------------- Kernel 2: ternary-quantize and scatter into Wbig (bf16) ----------------
// Wbig[p*C+o][ (p^wid)*C + c ] = sgn[wid][p] * ternary(w_wid[o][c]),  row-major [2048][2048]
__global__ void qb_build(const float* __restrict__ w0, const float* __restrict__ w1,
                         const float* __restrict__ w2, const float* __restrict__ w3,
                         const double* __restrict__ sums, unsigned short* __restrict__ Wb) {
    int t = blockIdx.x * 256 + threadIdx.x;     // [0, 32768)
    int o = t >> 6;                             // row within weight, [0,512)
    int c0 = (t & 63) << 3;                     // 8 consecutive cols
    const float sgn[4][4] = {{ 1.f, 1.f, 1.f, 1.f},
                             {-1.f, 1.f, 1.f,-1.f},
                             {-1.f,-1.f, 1.f, 1.f},
                             {-1.f, 1.f,-1.f, 1.f}};
    const float* wptr[4] = {w0, w1, w2, w3};
#pragma unroll
    for (int wid = 0; wid < 4; ++wid) {
        float mf = (float)(sums[wid * 2 + 1] * (1.0 / NW));
        float scf = fmaxf((float)(sums[wid * 2 + 0] * (1.0 / NW)), 1e-8f);
        const float* w = wptr[wid] + o * C + c0;
        float4v va = ((const float4v*)w)[0];
        float4v vb = ((const float4v*)w)[1];
        float q[8];
#pragma unroll
        for (int e = 0; e < 4; ++e) {
            q[e]     = rintf(fminf(fmaxf((va[e] - mf) / scf, -1.f), 1.f));
            q[4 + e] = rintf(fminf(fmaxf((vb[e] - mf) / scf, -1.f), 1.f));
        }
#pragma unroll
        for (int p = 0; p < 4; ++p) {
            int qb = p ^ wid;
            float s = sgn[wid][p];
            short8 v;
#pragma unroll
            for (int e = 0; e < 8; ++e) v[e] = (short)f2bf(s * q[e]);
            *(short8*)&Wb[(size_t)(p * C + o) * F + qb * C + c0] = v;
        }
    }
}

// ---------------- Kernel 3: GEMM  out[m][n] = sum_k x[m][k] * Wb[n][k] ----------------
// 128x128 tile, BK=32, 4 waves (2x2), 4x4 16x16x32 MFMA frags per wave.
// B staged via global_load_lds (bf16 in ws); A (fp32 x) reg-staged + cvt to bf16.
__global__ __launch_bounds__(256) void qb_gemm(
    const float* __restrict__ X, const unsigned short* __restrict__ Wb,
    const float* __restrict__ bias, const double* __restrict__ sums,
    float* __restrict__ out, int M) {
    constexpr int Kd = F, Nd = F;
    __shared__ unsigned short As[128 * 32];
    __shared__ unsigned short Bs[128 * 32];
    const int t = threadIdx.x;
    const int lane = t & 63, wv = t >> 6;

    const int nbn = Nd / 128;                   // 16
    const int nwg = gridDim.x;
    const int bid = blockIdx.x;
    const int swz = (bid & 7) * (nwg >> 3) + (bid >> 3);   // XCD swizzle (nwg%8==0)
    const int bm = swz / nbn, bn = swz % nbn;
    const int brow = bm * 128, bcol = bn * 128;

    const int wr = wv >> 1, wc = wv & 1;
    const int frow = lane & 15;
    const int k8 = (lane >> 4) << 3;

    f32x4 acc[4][4];
#pragma unroll
    for (int i = 0; i < 4; ++i)
#pragma unroll
        for (int j = 0; j < 4; ++j) acc[i][j] = (f32x4){0.f, 0.f, 0.f, 0.f};

    const int ar = t >> 3;           // 0..31
    const int ac = (t & 7) << 2;     // 0,4,...,28

    for (int kk = 0; kk < Kd; kk += 32) {
        // B tile: [128 n][32 k] bf16, direct global->LDS, 16B per lane
#pragma unroll
        for (int is = 0; is < 2; ++is) {
            int idx = is * 2048 + t * 8;
            int row = idx >> 5, col = idx & 31;
            const unsigned short* src = &Wb[(size_t)(bcol + row) * Kd + kk + col];
            __builtin_amdgcn_global_load_lds(
                (const __attribute__((address_space(1))) void*)src,
                (__attribute__((address_space(3))) void*)&Bs[idx], 16, 0, 0);
        }
        // A tile: [128 m][32 k], fp32 -> bf16 through registers
#pragma unroll
        for (int it = 0; it < 4; ++it) {
            int row = it * 32 + ar;
            float4v v = *(const float4v*)&X[(size_t)(brow + row) * Kd + kk + ac];
            ushort4v h;
            h[0] = f2bf(v[0]); h[1] = f2bf(v[1]); h[2] = f2bf(v[2]); h[3] = f2bf(v[3]);
            *(ushort4v*)&As[row * 32 + ac] = h;
        }
        __syncthreads();
        short8 a[4], b[4];
#pragma unroll
        for (int mi = 0; mi < 4; ++mi)
            a[mi] = *(const short8*)&As[(wr * 64 + mi * 16 + frow) * 32 + k8];
#pragma unroll
        for (int ni = 0; ni < 4; ++ni)
            b[ni] = *(const short8*)&Bs[(wc * 64 + ni * 16 + frow) * 32 + k8];
#pragma unroll
        for (int mi = 0; mi < 4; ++mi)
#pragma unroll
            for (int ni = 0; ni < 4; ++ni)
                acc[mi][ni] = __builtin_amdgcn_mfma_f32_16x16x32_bf16(
                    a[mi], b[ni], acc[mi][ni], 0, 0, 0);
        __syncthreads();
    }

    // epilogue: (acc + bias) * scale * 0.5
    float s0 = fmaxf((float)(sums[0] * (1.0 / NW)), 1e-8f);
    float s1 = fmaxf((float)(sums[2] * (1.0 / NW)), 1e-8f);
    float s2 = fmaxf((float)(sums[4] * (1.0 / NW)), 1e-8f);
    float s3 = fmaxf((float)(sums[6] * (1.0 / NW)), 1e-8f);
    float mul = (s0 + s1 + s2 + s3) * 0.25f * 0.5f;

#pragma unroll
    for (int ni = 0; ni < 4; ++ni) {
        int gcol = bcol + wc * 64 + ni * 16 + frow;
        float bv = bias[gcol];
#pragma unroll
        for (int mi = 0; mi < 4; ++mi) {
            int growb = brow + wr * 64 + mi * 16 + ((lane >> 4) << 2);
#pragma unroll
            for (int j = 0; j < 4; ++j)
                out[(size_t)(growb + j) * Nd + gcol] = (acc[mi][ni][j] + bv) * mul;
        }
    }
}

extern "C" void kernel_launch(void* const* d_in, const int* in_sizes, int n_in,
                              void* d_out, int out_size, void* d_ws, size_t ws_size,
                              hipStream_t stream) {
    const float* x    = (const float*)d_in[0];
    const float* wr_  = (const float*)d_in[1];
    const float* wi_  = (const float*)d_in[2];
    const float* wj_  = (const float*)d_in[3];
    const float* wk_  = (const float*)d_in[4];
    const float* bias = (const float*)d_in[5];
    float* out = (float*)d_out;
    const int M = in_sizes[0] / F;   // 16384

    double* sums = (double*)d_ws;                                  // 8 doubles
    unsigned short* Wb = (unsigned short*)((char*)d_ws + 1024);    // 2048*2048 bf16 = 8 MiB

    hipMemsetAsync(d_ws, 0, 64, stream);
    qb_sums<<<256, 256, 0, stream>>>(wr_, wi_, wj_, wk_, sums);
    qb_build<<<128, 256, 0, stream>>>(wr_, wi_, wj_, wk_, sums, Wb);
    const int grid = (M / 128) * (F / 128);                        // 2048
    qb_gemm<<<grid, 256, 0, stream>>>(x, Wb, bias, sums, out, M);
}

// Round 4
// 411.968 us; speedup vs baseline: 1.3159x; 1.3159x over previous
//
#include <hip/hip_runtime.h>
#include <hip/hip_bf16.h>
#include <stdint.h>

typedef __attribute__((ext_vector_type(8))) short short8;
typedef __attribute__((ext_vector_type(4))) float f32x4;
typedef __attribute__((ext_vector_type(4))) float float4v;
typedef __attribute__((ext_vector_type(4))) unsigned short ushort4v;

static constexpr int C = 512;
static constexpr int F = 2048;       // = N = K
static constexpr int NW = C * C;     // 262144 elements per weight

// RNE float -> bf16 bits (finite inputs)
__device__ inline unsigned short f2bf(float f) {
    union { float f; unsigned int u; } cv;
    cv.f = f;
    unsigned int r = cv.u + 0x7fffu + ((cv.u >> 16) & 1u);
    return (unsigned short)(r >> 16);
}

// ---------------- Kernel 1: per-weight sum(|w|), sum(w) in double ----------------
__global__ void qb_sums(const float* __restrict__ w0, const float* __restrict__ w1,
                        const float* __restrict__ w2, const float* __restrict__ w3,
                        double* __restrict__ sums) {
    int wid = blockIdx.x >> 6;
    int chunk = blockIdx.x & 63;
    const float* wsel = (wid == 0) ? w0 : (wid == 1) ? w1 : (wid == 2) ? w2 : w3;
    const float* p = wsel + chunk * (NW / 64);
    double sa = 0.0, sv = 0.0;
    for (int i = threadIdx.x; i < (NW / 64) / 4; i += 256) {
        float4v v = ((const float4v*)p)[i];
        sa += (double)fabsf(v.x) + fabsf(v.y) + fabsf(v.z) + fabsf(v.w);
        sv += (double)v.x + v.y + v.z + v.w;
    }
    for (int off = 32; off; off >>= 1) {
        sa += __shfl_down(sa, off);
        sv += __shfl_down(sv, off);
    }
    __shared__ double red[8];
    int wv = threadIdx.x >> 6;
    if ((threadIdx.x & 63) == 0) { red[wv] = sa; red[4 + wv] = sv; }
    __syncthreads();
    if (threadIdx.x == 0) {
        double tsa = red[0] + red[1] + red[2] + red[3];
        double tsv = red[4] + red[5] + red[6] + red[7];
        atomicAdd(&sums[wid * 2 + 0], tsa);
        atomicAdd(&sums[wid * 2 + 1], tsv);
    }
}

// ---------------- Kernel 2: ternary-quantize and scatter into Wbig (bf16) ----------------
// Wbig[p*C+o][ (p^wid)*C + c ] = sgn[wid][p] * ternary(w_wid[o][c]),  row-major [2048][2048]
__global__ void qb_build(const float* __restrict__ w0, const float* __restrict__ w1,
                         const float* __restrict__ w2, const float* __restrict__ w3,
                         const double* __restrict__ sums, unsigned short* __restrict__ Wb) {
    int wid = blockIdx.x >> 7;                       // 4 weights x 128 blocks
    int t = (blockIdx.x & 127) * 256 + threadIdx.x;  // [0, 32768)
    int o = t >> 6;
    int c0 = (t & 63) << 3;
    const float sgn[4][4] = {{ 1.f, 1.f, 1.f, 1.f},
                             {-1.f, 1.f, 1.f,-1.f},
                             {-1.f,-1.f, 1.f, 1.f},
                             {-1.f, 1.f,-1.f, 1.f}};
    const float* wptr[4] = {w0, w1, w2, w3};
    float mf = (float)(sums[wid * 2 + 1] * (1.0 / NW));
    float scf = fmaxf((float)(sums[wid * 2 + 0] * (1.0 / NW)), 1e-8f);
    const float* w = wptr[wid] + o * C + c0;
    float4v va = ((const float4v*)w)[0];
    float4v vb = ((const float4v*)w)[1];
    float q[8];
#pragma unroll
    for (int e = 0; e < 4; ++e) {
        q[e]     = rintf(fminf(fmaxf((va[e] - mf) / scf, -1.f), 1.f));
        q[4 + e] = rintf(fminf(fmaxf((vb[e] - mf) / scf, -1.f), 1.f));
    }
#pragma unroll
    for (int p = 0; p < 4; ++p) {
        int qb = p ^ wid;
        float s = sgn[wid][p];
        short8 v;
#pragma unroll
        for (int e = 0; e < 8; ++e) v[e] = (short)f2bf(s * q[e]);
        *(short8*)&Wb[(size_t)(p * C + o) * F + qb * C + c0] = v;
    }
}

// ---------------- Kernel 2b: X fp32 -> bf16 ----------------
__global__ void qb_convert(const float* __restrict__ X, unsigned short* __restrict__ Xb, int n8) {
    int stride = gridDim.x * blockDim.x;
    for (int i = blockIdx.x * blockDim.x + threadIdx.x; i < n8; i += stride) {
        float4v a = ((const float4v*)X)[2 * i];
        float4v b = ((const float4v*)X)[2 * i + 1];
        short8 h;
        h[0] = (short)f2bf(a[0]); h[1] = (short)f2bf(a[1]);
        h[2] = (short)f2bf(a[2]); h[3] = (short)f2bf(a[3]);
        h[4] = (short)f2bf(b[0]); h[5] = (short)f2bf(b[1]);
        h[6] = (short)f2bf(b[2]); h[7] = (short)f2bf(b[3]);
        ((short8*)Xb)[i] = h;
    }
}

// ---------------- Kernel 3 (fast): 256x256 8-phase GEMM, bf16 A and B ----------------
// out[m][n] = sum_k Xb[m][k] * Wb[n][k]; epilogue (.+bias)*mul.
// 8 waves (2M x 4N), per-wave C = 128x64 NON-CONTIGUOUS: rows {mh*128+wm*64+[0,64)},
// cols {nh*128+wn*32+[0,32)} so phase (mh,nh) consumes exactly A-half mh, B-half nh.
// LDS: 2 dbuf x (A 32KB + B 32KB) = 128 KiB. Stage = global_load_lds w16, linear dest,
// inverse-swizzled global source; ds_read applies c ^= (r&7)<<3 (bank-conflict-free).
// vmcnt(4) once per K-tile (2 half-tiles = 4 loads/wave in flight), never 0 in loop.
__global__ __launch_bounds__(512, 2) void qb_gemm256(
    const unsigned short* __restrict__ A,   // Xb [M][2048]
    const unsigned short* __restrict__ B,   // Wb [2048][2048]
    const float* __restrict__ bias, const double* __restrict__ sums,
    float* __restrict__ out) {
    constexpr int K = F, N = F, BK = 64, NT = K / BK;   // NT = 32
    __shared__ unsigned short As[2][256 * 64];
    __shared__ unsigned short Bs[2][256 * 64];

    const int tid = threadIdx.x;
    const int lane = tid & 63;
    const int w = tid >> 6;           // 0..7
    const int wm = w >> 2, wn = w & 3;

    const int nbn = N / 256;          // 8
    const int nwg = gridDim.x;        // multiple of 8
    const int bid = blockIdx.x;
    const int swz = (bid & 7) * (nwg >> 3) + (bid >> 3);
    const int bm = swz / nbn, bn = swz % nbn;
    const int brow = bm * 256, bcol = bn * 256;

    const int frow = lane & 15;
    const int fk = (lane >> 4) << 3;

    // stage one half-tile h of K-tile kt into ldsbase (linear dest, pre-swizzled src)
    auto stage = [&](const unsigned short* __restrict__ gbase, int growbase,
                     unsigned short* ldsbase, int h, int kt) {
        int ktw = kt & (NT - 1);      // wrap for tail (garbage never consumed)
#pragma unroll
        for (int l = 0; l < 2; ++l) {
            int boff = h * 16384 + (w * 2 + l) * 1024 + lane * 16;  // byte in tile
            int e = boff >> 1;
            int r = e >> 6, c = e & 63;
            int csrc = c ^ ((r & 7) << 3);
            const unsigned short* src = gbase + (size_t)(growbase + r) * K + ktw * BK + csrc;
            __builtin_amdgcn_global_load_lds(
                (const __attribute__((address_space(1))) void*)src,
                (__attribute__((address_space(3))) void*)((char*)ldsbase + boff),
                16, 0, 0);
        }
    };
    auto rdA = [&](int buf, int mh, int ks, int mi) -> short8 {
        int r = mh * 128 + wm * 64 + mi * 16 + frow;
        int cs = (ks * 32 + fk) ^ ((r & 7) << 3);
        return *(const short8*)&As[buf][r * 64 + cs];
    };
    auto rdB = [&](int buf, int nh, int ks, int ni) -> short8 {
        int r = nh * 128 + wn * 32 + ni * 16 + frow;
        int cs = (ks * 32 + fk) ^ ((r & 7) << 3);
        return *(const short8*)&Bs[buf][r * 64 + cs];
    };

    f32x4 acc[2][4][2][2];
#pragma unroll
    for (int a0 = 0; a0 < 2; ++a0)
#pragma unroll
        for (int a1 = 0; a1 < 4; ++a1)
#pragma unroll
            for (int a2 = 0; a2 < 2; ++a2)
#pragma unroll
                for (int a3 = 0; a3 < 2; ++a3) acc[a0][a1][a2][a3] = (f32x4){0.f, 0.f, 0.f, 0.f};

    unsigned short* A0p = &As[0][0];
    unsigned short* A1p = &As[1][0];
    unsigned short* B0p = &Bs[0][0];
    unsigned short* B1p = &Bs[1][0];

    // Prologue. Issue order = steady-state order: B0(0),A0(0),A1(0),B1(0),B0(1),A0(1).
    stage(B, bcol, B0p, 0, 0);
    stage(A, brow, A0p, 0, 0);
    stage(A, brow, A0p, 1, 0);
    stage(B, bcol, B0p, 1, 0);
    stage(B, bcol, B1p, 0, 1);
    stage(A, brow, A1p, 0, 1);
    asm volatile("s_waitcnt vmcnt(4)" ::: "memory");   // tile 0 fully resident
    __builtin_amdgcn_s_barrier();

#define QB_PHASE(BUFC, MH, NH, STAGE_STMT, TILE_END)                                   \
    {                                                                                  \
        short8 af[2][4], bq[2][2];                                                     \
        _Pragma("unroll") for (int ks = 0; ks < 2; ++ks) {                             \
            _Pragma("unroll") for (int mi = 0; mi < 4; ++mi)                           \
                af[ks][mi] = rdA(BUFC, MH, ks, mi);                                    \
            _Pragma("unroll") for (int ni = 0; ni < 2; ++ni)                           \
                bq[ks][ni] = rdB(BUFC, NH, ks, ni);                                    \
        }                                                                              \
        STAGE_STMT;                                                                    \
        __builtin_amdgcn_s_barrier();                                                  \
        asm volatile("s_waitcnt lgkmcnt(0)" ::: "memory");                             \
        __builtin_amdgcn_sched_barrier(0);                                             \
        __builtin_amdgcn_s_setprio(1);                                                 \
        _Pragma("unroll") for (int ks = 0; ks < 2; ++ks)                               \
            _Pragma("unroll") for (int mi = 0; mi < 4; ++mi)                           \
                _Pragma("unroll") for (int ni = 0; ni < 2; ++ni)                       \
                    acc[MH][mi][NH][ni] = __builtin_amdgcn_mfma_f32_16x16x32_bf16(     \
                        af[ks][mi], bq[ks][ni], acc[MH][mi][NH][ni], 0, 0, 0);         \
        __builtin_amdgcn_s_setprio(0);                                                 \
        TILE_END;                                                                      \
        __builtin_amdgcn_s_barrier();                                                  \
    }

    for (int it = 0; it < NT / 2; ++it) {
        int kt0 = 2 * it;
        // ---- tile kt0 (buf0) ----
        QB_PHASE(0, 0, 0, stage(A, brow, A1p, 1, kt0 + 1), ((void)0))   // A1(kt+1)->buf1
        QB_PHASE(0, 1, 0, stage(B, bcol, B1p, 1, kt0 + 1), ((void)0))   // B1(kt+1)->buf1
        QB_PHASE(0, 0, 1, stage(B, bcol, B0p, 0, kt0 + 2), ((void)0))   // B0(kt+2)->buf0
        QB_PHASE(0, 1, 1, stage(A, brow, A0p, 0, kt0 + 2),
                 asm volatile("s_waitcnt vmcnt(4)" ::: "memory"))       // A0(kt+2)->buf0
        // ---- tile kt0+1 (buf1) ----
        QB_PHASE(1, 0, 0, stage(A, brow, A0p, 1, kt0 + 2), ((void)0))   // A1(kt+2)->buf0
        QB_PHASE(1, 1, 0, stage(B, bcol, B0p, 1, kt0 + 2), ((void)0))   // B1(kt+2)->buf0
        QB_PHASE(1, 0, 1, stage(B, bcol, B1p, 0, kt0 + 3), ((void)0))   // B0(kt+3)->buf1
        QB_PHASE(1, 1, 1, stage(A, brow, A1p, 0, kt0 + 3),
                 asm volatile("s_waitcnt vmcnt(4)" ::: "memory"))       // A0(kt+3)->buf1
    }
#undef QB_PHASE

    float s0 = fmaxf((float)(sums[0] * (1.0 / NW)), 1e-8f);
    float s1 = fmaxf((float)(sums[2] * (1.0 / NW)), 1e-8f);
    float s2 = fmaxf((float)(sums[4] * (1.0 / NW)), 1e-8f);
    float s3 = fmaxf((float)(sums[6] * (1.0 / NW)), 1e-8f);
    float mul = (s0 + s1 + s2 + s3) * 0.25f * 0.5f;

#pragma unroll
    for (int mh = 0; mh < 2; ++mh)
#pragma unroll
        for (int nh = 0; nh < 2; ++nh)
#pragma unroll
            for (int ni = 0; ni < 2; ++ni) {
                int gcol = bcol + nh * 128 + wn * 32 + ni * 16 + frow;
                float bv = bias[gcol];
#pragma unroll
                for (int mi = 0; mi < 4; ++mi) {
                    int gr0 = brow + mh * 128 + wm * 64 + mi * 16 + ((lane >> 4) << 2);
#pragma unroll
                    for (int j = 0; j < 4; ++j)
                        out[(size_t)(gr0 + j) * N + gcol] = (acc[mh][mi][nh][ni][j] + bv) * mul;
                }
            }
}

// ---------------- Kernel 3 (fallback, verified round-3): 128x128 GEMM ----------------
__global__ __launch_bounds__(256) void qb_gemm(
    const float* __restrict__ X, const unsigned short* __restrict__ Wb,
    const float* __restrict__ bias, const double* __restrict__ sums,
    float* __restrict__ out, int M) {
    constexpr int Kd = F, Nd = F;
    __shared__ unsigned short As[128 * 32];
    __shared__ unsigned short Bs[128 * 32];
    const int t = threadIdx.x;
    const int lane = t & 63, wv = t >> 6;
    const int nbn = Nd / 128;
    const int nwg = gridDim.x;
    const int bid = blockIdx.x;
    const int swz = (bid & 7) * (nwg >> 3) + (bid >> 3);
    const int bm = swz / nbn, bn = swz % nbn;
    const int brow = bm * 128, bcol = bn * 128;
    const int wr = wv >> 1, wc = wv & 1;
    const int frow = lane & 15;
    const int k8 = (lane >> 4) << 3;
    f32x4 acc[4][4];
#pragma unroll
    for (int i = 0; i < 4; ++i)
#pragma unroll
        for (int j = 0; j < 4; ++j) acc[i][j] = (f32x4){0.f, 0.f, 0.f, 0.f};
    const int ar = t >> 3;
    const int ac = (t & 7) << 2;
    for (int kk = 0; kk < Kd; kk += 32) {
#pragma unroll
        for (int is = 0; is < 2; ++is) {
            int idx = is * 2048 + t * 8;
            int row = idx >> 5, col = idx & 31;
            const unsigned short* src = &Wb[(size_t)(bcol + row) * Kd + kk + col];
            __builtin_amdgcn_global_load_lds(
                (const __attribute__((address_space(1))) void*)src,
                (__attribute__((address_space(3))) void*)&Bs[idx], 16, 0, 0);
        }
#pragma unroll
        for (int it = 0; it < 4; ++it) {
            int row = it * 32 + ar;
            float4v v = *(const float4v*)&X[(size_t)(brow + row) * Kd + kk + ac];
            ushort4v h;
            h[0] = f2bf(v[0]); h[1] = f2bf(v[1]); h[2] = f2bf(v[2]); h[3] = f2bf(v[3]);
            *(ushort4v*)&As[row * 32 + ac] = h;
        }
        __syncthreads();
        short8 a[4], b[4];
#pragma unroll
        for (int mi = 0; mi < 4; ++mi)
            a[mi] = *(const short8*)&As[(wr * 64 + mi * 16 + frow) * 32 + k8];
#pragma unroll
        for (int ni = 0; ni < 4; ++ni)
            b[ni] = *(const short8*)&Bs[(wc * 64 + ni * 16 + frow) * 32 + k8];
#pragma unroll
        for (int mi = 0; mi < 4; ++mi)
#pragma unroll
            for (int ni = 0; ni < 4; ++ni)
                acc[mi][ni] = __builtin_amdgcn_mfma_f32_16x16x32_bf16(
                    a[mi], b[ni], acc[mi][ni], 0, 0, 0);
        __syncthreads();
    }
    float s0 = fmaxf((float)(sums[0] * (1.0 / NW)), 1e-8f);
    float s1 = fmaxf((float)(sums[2] * (1.0 / NW)), 1e-8f);
    float s2 = fmaxf((float)(sums[4] * (1.0 / NW)), 1e-8f);
    float s3 = fmaxf((float)(sums[6] * (1.0 / NW)), 1e-8f);
    float mul = (s0 + s1 + s2 + s3) * 0.25f * 0.5f;
#pragma unroll
    for (int ni = 0; ni < 4; ++ni) {
        int gcol = bcol + wc * 64 + ni * 16 + frow;
        float bv = bias[gcol];
#pragma unroll
        for (int mi = 0; mi < 4; ++mi) {
            int growb = brow + wr * 64 + mi * 16 + ((lane >> 4) << 2);
#pragma unroll
            for (int j = 0; j < 4; ++j)
                out[(size_t)(growb + j) * Nd + gcol] = (acc[mi][ni][j] + bv) * mul;
        }
    }
}

extern "C" void kernel_launch(void* const* d_in, const int* in_sizes, int n_in,
                              void* d_out, int out_size, void* d_ws, size_t ws_size,
                              hipStream_t stream) {
    const float* x    = (const float*)d_in[0];
    const float* wr_  = (const float*)d_in[1];
    const float* wi_  = (const float*)d_in[2];
    const float* wj_  = (const float*)d_in[3];
    const float* wk_  = (const float*)d_in[4];
    const float* bias = (const float*)d_in[5];
    float* out = (float*)d_out;
    const int M = in_sizes[0] / F;   // 16384

    const size_t WB_OFF = 4096;
    const size_t XB_OFF = WB_OFF + (size_t)F * F * 2;          // + 8 MiB
    const size_t NEED   = XB_OFF + (size_t)M * F * 2;          // + 64 MiB

    double* sums = (double*)d_ws;
    unsigned short* Wb = (unsigned short*)((char*)d_ws + WB_OFF);

    hipMemsetAsync(d_ws, 0, 64, stream);
    qb_sums<<<256, 256, 0, stream>>>(wr_, wi_, wj_, wk_, sums);
    qb_build<<<512, 256, 0, stream>>>(wr_, wi_, wj_, wk_, sums, Wb);

    if (ws_size >= NEED && (M % 256) == 0) {
        unsigned short* Xb = (unsigned short*)((char*)d_ws + XB_OFF);
        qb_convert<<<2048, 256, 0, stream>>>(x, Xb, (M * F) / 8);
        const int grid = (M / 256) * (F / 256);                // 512, %8==0
        qb_gemm256<<<grid, 512, 0, stream>>>(Xb, Wb, bias, sums, out);
    } else {
        const int grid = (M / 128) * (F / 128);
        qb_gemm<<<grid, 256, 0, stream>>>(x, Wb, bias, sums, out, M);
    }
}

// Round 5
// 387.599 us; speedup vs baseline: 1.3986x; 1.0629x over previous
//
#include <hip/hip_runtime.h>
#include <hip/hip_bf16.h>
#include <stdint.h>

typedef __attribute__((ext_vector_type(8))) short short8;
typedef __attribute__((ext_vector_type(4))) float f32x4;
typedef __attribute__((ext_vector_type(4))) float float4v;
typedef __attribute__((ext_vector_type(4))) unsigned short ushort4v;

static constexpr int C = 512;
static constexpr int F = 2048;       // = N = K
static constexpr int NW = C * C;     // 262144 elements per weight

// RNE float -> bf16 bits (finite inputs)
__device__ inline unsigned short f2bf(float f) {
    union { float f; unsigned int u; } cv;
    cv.f = f;
    unsigned int r = cv.u + 0x7fffu + ((cv.u >> 16) & 1u);
    return (unsigned short)(r >> 16);
}

// ---------------- Kernel 1: fused {X fp32->bf16 convert} ∥ {per-weight partial sums} ----
// blocks [0,2048): grid-stride convert; blocks [2048,2304): 64 chunks x 4 weights,
// partial sum(|w|),sum(w) in double -> part[b*2+{0,1}] (no atomics, no memset needed).
__global__ void qb_prep(const float* __restrict__ X, unsigned short* __restrict__ Xb, int n8,
                        const float* __restrict__ w0, const float* __restrict__ w1,
                        const float* __restrict__ w2, const float* __restrict__ w3,
                        double* __restrict__ part) {
    __shared__ double red[8];
    if (blockIdx.x >= 2048) {
        int b = blockIdx.x - 2048;       // 0..255
        int wid = b >> 6, chunk = b & 63;
        const float* wsel = (wid == 0) ? w0 : (wid == 1) ? w1 : (wid == 2) ? w2 : w3;
        const float* p = wsel + chunk * (NW / 64);
        double sa = 0.0, sv = 0.0;
        for (int i = threadIdx.x; i < (NW / 64) / 4; i += 256) {
            float4v v = ((const float4v*)p)[i];
            sa += (double)fabsf(v.x) + fabsf(v.y) + fabsf(v.z) + fabsf(v.w);
            sv += (double)v.x + v.y + v.z + v.w;
        }
        for (int off = 32; off; off >>= 1) {
            sa += __shfl_down(sa, off);
            sv += __shfl_down(sv, off);
        }
        int wv = threadIdx.x >> 6;
        if ((threadIdx.x & 63) == 0) { red[wv] = sa; red[4 + wv] = sv; }
        __syncthreads();
        if (threadIdx.x == 0) {
            part[b * 2 + 0] = red[0] + red[1] + red[2] + red[3];
            part[b * 2 + 1] = red[4] + red[5] + red[6] + red[7];
        }
        return;
    }
    int stride = 2048 * 256;
    for (int i = blockIdx.x * 256 + threadIdx.x; i < n8; i += stride) {
        float4v a = ((const float4v*)X)[2 * i];
        float4v b = ((const float4v*)X)[2 * i + 1];
        short8 h;
        h[0] = (short)f2bf(a[0]); h[1] = (short)f2bf(a[1]);
        h[2] = (short)f2bf(a[2]); h[3] = (short)f2bf(a[3]);
        h[4] = (short)f2bf(b[0]); h[5] = (short)f2bf(b[1]);
        h[6] = (short)f2bf(b[2]); h[7] = (short)f2bf(b[3]);
        ((short8*)Xb)[i] = h;
    }
}

// ---------------- Kernel 2: ternary-quantize and scatter into Wbig (bf16) ----------------
// Wbig[p*C+o][ (p^wid)*C + c ] = sgn[wid][p] * ternary(w_wid[o][c]); also publish scf->finals.
__global__ void qb_build(const float* __restrict__ w0, const float* __restrict__ w1,
                         const float* __restrict__ w2, const float* __restrict__ w3,
                         const double* __restrict__ part, unsigned short* __restrict__ Wb,
                         double* __restrict__ finals) {
    int wid = blockIdx.x >> 7;                       // 4 weights x 128 blocks
    int t = (blockIdx.x & 127) * 256 + threadIdx.x;  // [0, 32768)
    int o = t >> 6;
    int c0 = (t & 63) << 3;
    double sa = 0.0, sv = 0.0;
#pragma unroll
    for (int i = 0; i < 64; ++i) {
        sa += part[(wid * 64 + i) * 2 + 0];
        sv += part[(wid * 64 + i) * 2 + 1];
    }
    float mf = (float)(sv * (1.0 / NW));
    float scf = fmaxf((float)(sa * (1.0 / NW)), 1e-8f);
    if ((blockIdx.x & 127) == 0 && threadIdx.x == 0) finals[wid] = (double)scf;

    const float sgn[4][4] = {{ 1.f, 1.f, 1.f, 1.f},
                             {-1.f, 1.f, 1.f,-1.f},
                             {-1.f,-1.f, 1.f, 1.f},
                             {-1.f, 1.f,-1.f, 1.f}};
    const float* wptr[4] = {w0, w1, w2, w3};
    const float* w = wptr[wid] + o * C + c0;
    float4v va = ((const float4v*)w)[0];
    float4v vb = ((const float4v*)w)[1];
    float q[8];
#pragma unroll
    for (int e = 0; e < 4; ++e) {
        q[e]     = rintf(fminf(fmaxf((va[e] - mf) / scf, -1.f), 1.f));
        q[4 + e] = rintf(fminf(fmaxf((vb[e] - mf) / scf, -1.f), 1.f));
    }
#pragma unroll
    for (int p = 0; p < 4; ++p) {
        int qb = p ^ wid;
        float s = sgn[wid][p];
        short8 v;
#pragma unroll
        for (int e = 0; e < 8; ++e) v[e] = (short)f2bf(s * q[e]);
        *(short8*)&Wb[(size_t)(p * C + o) * F + qb * C + c0] = v;
    }
}

// ---------------- Kernel 3 (fast): 256x256 8-phase GEMM, minimum-LDS-read schedule ------
// Per K-tile (4 phases): q0 reads A-h0(8), q1 B-h1(4), q2 A-h1(8), q3 none; B-h0 of the
// NEXT tile is read in q3 after vmcnt(4) (next tile guaranteed resident). B halves held in
// regs across the tile, A-half reused over 2 phases -> 24 ds_read_b128/tile (min) vs 48.
// Stage/barrier/vmcnt skeleton identical to the HW-proven round-4 kernel.
__global__ __launch_bounds__(512, 2) void qb_gemm256(
    const unsigned short* __restrict__ A,   // Xb [M][2048]
    const unsigned short* __restrict__ B,   // Wb [2048][2048]
    const float* __restrict__ bias, const double* __restrict__ finals,
    float* __restrict__ out) {
    constexpr int K = F, N = F, BK = 64, NT = K / BK;   // NT = 32
    __shared__ unsigned short As[2][256 * 64];
    __shared__ unsigned short Bs[2][256 * 64];

    const int tid = threadIdx.x;
    const int lane = tid & 63;
    const int w = tid >> 6;           // 0..7
    const int wm = w >> 2, wn = w & 3;

    const int nbn = N / 256;          // 8
    const int nwg = gridDim.x;        // multiple of 8
    const int bid = blockIdx.x;
    const int swz = (bid & 7) * (nwg >> 3) + (bid >> 3);
    const int bm = swz / nbn, bn = swz % nbn;
    const int brow = bm * 256, bcol = bn * 256;

    const int frow = lane & 15;
    const int fk = (lane >> 4) << 3;

    auto stage = [&](const unsigned short* __restrict__ gbase, int growbase,
                     unsigned short* ldsbase, int h, int kt) {
        int ktw = kt & (NT - 1);
#pragma unroll
        for (int l = 0; l < 2; ++l) {
            int boff = h * 16384 + (w * 2 + l) * 1024 + lane * 16;
            int e = boff >> 1;
            int r = e >> 6, c = e & 63;
            int csrc = c ^ ((r & 7) << 3);
            const unsigned short* src = gbase + (size_t)(growbase + r) * K + ktw * BK + csrc;
            __builtin_amdgcn_global_load_lds(
                (const __attribute__((address_space(1))) void*)src,
                (__attribute__((address_space(3))) void*)((char*)ldsbase + boff),
                16, 0, 0);
        }
    };
    auto rdA = [&](int buf, int mh, int ks, int mi) -> short8 {
        int r = mh * 128 + wm * 64 + mi * 16 + frow;
        int cs = (ks * 32 + fk) ^ ((r & 7) << 3);
        return *(const short8*)&As[buf][r * 64 + cs];
    };
    auto rdB = [&](int buf, int nh, int ks, int ni) -> short8 {
        int r = nh * 128 + wn * 32 + ni * 16 + frow;
        int cs = (ks * 32 + fk) ^ ((r & 7) << 3);
        return *(const short8*)&Bs[buf][r * 64 + cs];
    };

    f32x4 acc[2][4][2][2];
#pragma unroll
    for (int a0 = 0; a0 < 2; ++a0)
#pragma unroll
        for (int a1 = 0; a1 < 4; ++a1)
#pragma unroll
            for (int a2 = 0; a2 < 2; ++a2)
#pragma unroll
                for (int a3 = 0; a3 < 2; ++a3) acc[a0][a1][a2][a3] = (f32x4){0.f, 0.f, 0.f, 0.f};

    // Prologue (unchanged, proven): 12 loads out; vmcnt(4) => tile0 resident, 4 in flight.
    stage(B, bcol, &Bs[0][0], 0, 0);
    stage(A, brow, &As[0][0], 0, 0);
    stage(A, brow, &As[0][0], 1, 0);
    stage(B, bcol, &Bs[0][0], 1, 0);
    stage(B, bcol, &Bs[1][0], 0, 1);
    stage(A, brow, &As[1][0], 0, 1);
    asm volatile("s_waitcnt vmcnt(4)" ::: "memory");
    __builtin_amdgcn_s_barrier();

    short8 af[2][4], b0[2][2], b1[2][2];
#pragma unroll
    for (int ks = 0; ks < 2; ++ks)
#pragma unroll
        for (int ni = 0; ni < 2; ++ni) b0[ks][ni] = rdB(0, 0, ks, ni);

#define QB_MFMA(MH, NH, BB)                                                            \
    _Pragma("unroll") for (int ks = 0; ks < 2; ++ks)                                   \
        _Pragma("unroll") for (int mi = 0; mi < 4; ++mi)                               \
            _Pragma("unroll") for (int ni = 0; ni < 2; ++ni)                           \
                acc[MH][mi][NH][ni] = __builtin_amdgcn_mfma_f32_16x16x32_bf16(         \
                    af[ks][mi], BB[ks][ni], acc[MH][mi][NH][ni], 0, 0, 0);

#define QB_TILE(CB, KT)                                                                \
    /* q0: read A-h0; MFMA (0,0) with held b0 */                                       \
    _Pragma("unroll") for (int ks = 0; ks < 2; ++ks)                                   \
        _Pragma("unroll") for (int mi = 0; mi < 4; ++mi) af[ks][mi] = rdA(CB, 0, ks, mi); \
    stage(A, brow, &As[1 - (CB)][0], 1, (KT) + 1);                                     \
    __builtin_amdgcn_s_barrier();                                                      \
    asm volatile("s_waitcnt lgkmcnt(0)" ::: "memory");                                 \
    __builtin_amdgcn_sched_barrier(0);                                                 \
    __builtin_amdgcn_s_setprio(1);                                                     \
    QB_MFMA(0, 0, b0)                                                                  \
    __builtin_amdgcn_s_setprio(0);                                                     \
    __builtin_amdgcn_s_barrier();                                                      \
    /* q1: read B-h1; MFMA (0,1) reusing af */                                         \
    _Pragma("unroll") for (int ks = 0; ks < 2; ++ks)                                   \
        _Pragma("unroll") for (int ni = 0; ni < 2; ++ni) b1[ks][ni] = rdB(CB, 1, ks, ni); \
    stage(B, bcol, &Bs[1 - (CB)][0], 1, (KT) + 1);                                     \
    __builtin_amdgcn_s_barrier();                                                      \
    asm volatile("s_waitcnt lgkmcnt(0)" ::: "memory");                                 \
    __builtin_amdgcn_sched_barrier(0);                                                 \
    __builtin_amdgcn_s_setprio(1);                                                     \
    QB_MFMA(0, 1, b1)                                                                  \
    __builtin_amdgcn_s_setprio(0);                                                     \
    __builtin_amdgcn_s_barrier();                                                      \
    /* q2: read A-h1; MFMA (1,1) reusing b1 */                                         \
    _Pragma("unroll") for (int ks = 0; ks < 2; ++ks)                                   \
        _Pragma("unroll") for (int mi = 0; mi < 4; ++mi) af[ks][mi] = rdA(CB, 1, ks, mi); \
    stage(B, bcol, &Bs[CB][0], 0, (KT) + 2);                                           \
    __builtin_amdgcn_s_barrier();                                                      \
    asm volatile("s_waitcnt lgkmcnt(0)" ::: "memory");                                 \
    __builtin_amdgcn_sched_barrier(0);                                                 \
    __builtin_amdgcn_s_setprio(1);                                                     \
    QB_MFMA(1, 1, b1)                                                                  \
    __builtin_amdgcn_s_setprio(0);                                                     \
    __builtin_amdgcn_s_barrier();                                                      \
    /* q3: no reads; MFMA (1,0); then prefetch next tile's B-h0 after vmcnt(4) */      \
    stage(A, brow, &As[CB][0], 0, (KT) + 2);                                           \
    __builtin_amdgcn_s_barrier();                                                      \
    __builtin_amdgcn_s_setprio(1);                                                     \
    QB_MFMA(1, 0, b0)                                                                  \
    __builtin_amdgcn_s_setprio(0);                                                     \
    asm volatile("s_waitcnt vmcnt(4)" ::: "memory");                                   \
    _Pragma("unroll") for (int ks = 0; ks < 2; ++ks)                                   \
        _Pragma("unroll") for (int ni = 0; ni < 2; ++ni) b0[ks][ni] = rdB(1 - (CB), 0, ks, ni); \
    __builtin_amdgcn_s_barrier();

    for (int it = 0; it < NT / 2; ++it) {
        int kt0 = 2 * it;
        QB_TILE(0, kt0)
        QB_TILE(1, kt0 + 1)
    }
#undef QB_TILE
#undef QB_MFMA

    float mul = (float)((finals[0] + finals[1] + finals[2] + finals[3]) * (0.25 * 0.5));

#pragma unroll
    for (int mh = 0; mh < 2; ++mh)
#pragma unroll
        for (int nh = 0; nh < 2; ++nh)
#pragma unroll
            for (int ni = 0; ni < 2; ++ni) {
                int gcol = bcol + nh * 128 + wn * 32 + ni * 16 + frow;
                float bv = bias[gcol];
#pragma unroll
                for (int mi = 0; mi < 4; ++mi) {
                    int gr0 = brow + mh * 128 + wm * 64 + mi * 16 + ((lane >> 4) << 2);
#pragma unroll
                    for (int j = 0; j < 4; ++j)
                        out[(size_t)(gr0 + j) * N + gcol] = (acc[mh][mi][nh][ni][j] + bv) * mul;
                }
            }
}

// ---------------- Kernel 3 (fallback): 128x128 GEMM, fp32 X in-loop convert ----------------
__global__ __launch_bounds__(256) void qb_gemm(
    const float* __restrict__ X, const unsigned short* __restrict__ Wb,
    const float* __restrict__ bias, const double* __restrict__ finals,
    float* __restrict__ out, int M) {
    constexpr int Kd = F, Nd = F;
    __shared__ unsigned short As[128 * 32];
    __shared__ unsigned short Bs[128 * 32];
    const int t = threadIdx.x;
    const int lane = t & 63, wv = t >> 6;
    const int nbn = Nd / 128;
    const int nwg = gridDim.x;
    const int bid = blockIdx.x;
    const int swz = (bid & 7) * (nwg >> 3) + (bid >> 3);
    const int bm = swz / nbn, bn = swz % nbn;
    const int brow = bm * 128, bcol = bn * 128;
    const int wr = wv >> 1, wc = wv & 1;
    const int frow = lane & 15;
    const int k8 = (lane >> 4) << 3;
    f32x4 acc[4][4];
#pragma unroll
    for (int i = 0; i < 4; ++i)
#pragma unroll
        for (int j = 0; j < 4; ++j) acc[i][j] = (f32x4){0.f, 0.f, 0.f, 0.f};
    const int ar = t >> 3;
    const int ac = (t & 7) << 2;
    for (int kk = 0; kk < Kd; kk += 32) {
#pragma unroll
        for (int is = 0; is < 2; ++is) {
            int idx = is * 2048 + t * 8;
            int row = idx >> 5, col = idx & 31;
            const unsigned short* src = &Wb[(size_t)(bcol + row) * Kd + kk + col];
            __builtin_amdgcn_global_load_lds(
                (const __attribute__((address_space(1))) void*)src,
                (__attribute__((address_space(3))) void*)&Bs[idx], 16, 0, 0);
        }
#pragma unroll
        for (int it = 0; it < 4; ++it) {
            int row = it * 32 + ar;
            float4v v = *(const float4v*)&X[(size_t)(brow + row) * Kd + kk + ac];
            ushort4v h;
            h[0] = f2bf(v[0]); h[1] = f2bf(v[1]); h[2] = f2bf(v[2]); h[3] = f2bf(v[3]);
            *(ushort4v*)&As[row * 32 + ac] = h;
        }
        __syncthreads();
        short8 a[4], b[4];
#pragma unroll
        for (int mi = 0; mi < 4; ++mi)
            a[mi] = *(const short8*)&As[(wr * 64 + mi * 16 + frow) * 32 + k8];
#pragma unroll
        for (int ni = 0; ni < 4; ++ni)
            b[ni] = *(const short8*)&Bs[(wc * 64 + ni * 16 + frow) * 32 + k8];
#pragma unroll
        for (int mi = 0; mi < 4; ++mi)
#pragma unroll
            for (int ni = 0; ni < 4; ++ni)
                acc[mi][ni] = __builtin_amdgcn_mfma_f32_16x16x32_bf16(
                    a[mi], b[ni], acc[mi][ni], 0, 0, 0);
        __syncthreads();
    }
    float mul = (float)((finals[0] + finals[1] + finals[2] + finals[3]) * (0.25 * 0.5));
#pragma unroll
    for (int ni = 0; ni < 4; ++ni) {
        int gcol = bcol + wc * 64 + ni * 16 + frow;
        float bv = bias[gcol];
#pragma unroll
        for (int mi = 0; mi < 4; ++mi) {
            int growb = brow + wr * 64 + mi * 16 + ((lane >> 4) << 2);
#pragma unroll
            for (int j = 0; j < 4; ++j)
                out[(size_t)(growb + j) * Nd + gcol] = (acc[mi][ni][j] + bv) * mul;
        }
    }
}

extern "C" void kernel_launch(void* const* d_in, const int* in_sizes, int n_in,
                              void* d_out, int out_size, void* d_ws, size_t ws_size,
                              hipStream_t stream) {
    const float* x    = (const float*)d_in[0];
    const float* wr_  = (const float*)d_in[1];
    const float* wi_  = (const float*)d_in[2];
    const float* wj_  = (const float*)d_in[3];
    const float* wk_  = (const float*)d_in[4];
    const float* bias = (const float*)d_in[5];
    float* out = (float*)d_out;
    const int M = in_sizes[0] / F;   // 16384

    const size_t FIN_OFF = 4096;                               // part: [0,4096)
    const size_t WB_OFF  = 8192;
    const size_t XB_OFF  = WB_OFF + (size_t)F * F * 2;         // + 8 MiB
    const size_t NEED    = XB_OFF + (size_t)M * F * 2;         // + 64 MiB

    double* part   = (double*)d_ws;
    double* finals = (double*)((char*)d_ws + FIN_OFF);
    unsigned short* Wb = (unsigned short*)((char*)d_ws + WB_OFF);
    unsigned short* Xb = (unsigned short*)((char*)d_ws + XB_OFF);

    const bool fast = (ws_size >= NEED) && (M % 256) == 0;

    qb_prep<<<2304, 256, 0, stream>>>(x, Xb, fast ? (M * F) / 8 : 0,
                                      wr_, wi_, wj_, wk_, part);
    qb_build<<<512, 256, 0, stream>>>(wr_, wi_, wj_, wk_, part, Wb, finals);

    if (fast) {
        const int grid = (M / 256) * (F / 256);                // 512, %8==0
        qb_gemm256<<<grid, 512, 0, stream>>>(Xb, Wb, bias, finals, out);
    } else {
        const int grid = (M / 128) * (F / 128);
        qb_gemm<<<grid, 256, 0, stream>>>(x, Wb, bias, finals, out, M);
    }
}

// Round 6
// 364.969 us; speedup vs baseline: 1.4853x; 1.0620x over previous
//
#include <hip/hip_runtime.h>
#include <hip/hip_bf16.h>
#include <stdint.h>

typedef __attribute__((ext_vector_type(8))) short short8;
typedef __attribute__((ext_vector_type(4))) float f32x4;
typedef __attribute__((ext_vector_type(4))) float float4v;
typedef __attribute__((ext_vector_type(4))) unsigned short ushort4v;

static constexpr int C = 512;
static constexpr int F = 2048;       // = N = K
static constexpr int NW = C * C;     // 262144 elements per weight

// RNE float -> bf16 bits (finite inputs)
__device__ inline unsigned short f2bf(float f) {
    union { float f; unsigned int u; } cv;
    cv.f = f;
    unsigned int r = cv.u + 0x7fffu + ((cv.u >> 16) & 1u);
    return (unsigned short)(r >> 16);
}

// ---------------- Kernel 1: fused {X fp32->bf16 convert} ∥ {per-weight partial sums} ----
__global__ void qb_prep(const float* __restrict__ X, unsigned short* __restrict__ Xb, int n8,
                        const float* __restrict__ w0, const float* __restrict__ w1,
                        const float* __restrict__ w2, const float* __restrict__ w3,
                        double* __restrict__ part) {
    __shared__ double red[8];
    if (blockIdx.x >= 2048) {
        int b = blockIdx.x - 2048;       // 0..255
        int wid = b >> 6, chunk = b & 63;
        const float* wsel = (wid == 0) ? w0 : (wid == 1) ? w1 : (wid == 2) ? w2 : w3;
        const float* p = wsel + chunk * (NW / 64);
        double sa = 0.0, sv = 0.0;
        for (int i = threadIdx.x; i < (NW / 64) / 4; i += 256) {
            float4v v = ((const float4v*)p)[i];
            sa += (double)fabsf(v.x) + fabsf(v.y) + fabsf(v.z) + fabsf(v.w);
            sv += (double)v.x + v.y + v.z + v.w;
        }
        for (int off = 32; off; off >>= 1) {
            sa += __shfl_down(sa, off);
            sv += __shfl_down(sv, off);
        }
        int wv = threadIdx.x >> 6;
        if ((threadIdx.x & 63) == 0) { red[wv] = sa; red[4 + wv] = sv; }
        __syncthreads();
        if (threadIdx.x == 0) {
            part[b * 2 + 0] = red[0] + red[1] + red[2] + red[3];
            part[b * 2 + 1] = red[4] + red[5] + red[6] + red[7];
        }
        return;
    }
    int stride = 2048 * 256;
    for (int i = blockIdx.x * 256 + threadIdx.x; i < n8; i += stride) {
        float4v a = ((const float4v*)X)[2 * i];
        float4v b = ((const float4v*)X)[2 * i + 1];
        short8 h;
        h[0] = (short)f2bf(a[0]); h[1] = (short)f2bf(a[1]);
        h[2] = (short)f2bf(a[2]); h[3] = (short)f2bf(a[3]);
        h[4] = (short)f2bf(b[0]); h[5] = (short)f2bf(b[1]);
        h[6] = (short)f2bf(b[2]); h[7] = (short)f2bf(b[3]);
        ((short8*)Xb)[i] = h;
    }
}

// ---------------- Kernel 2: ternary-quantize and scatter into Wbig (bf16) ----------------
__global__ void qb_build(const float* __restrict__ w0, const float* __restrict__ w1,
                         const float* __restrict__ w2, const float* __restrict__ w3,
                         const double* __restrict__ part, unsigned short* __restrict__ Wb,
                         double* __restrict__ finals) {
    int wid = blockIdx.x >> 7;
    int t = (blockIdx.x & 127) * 256 + threadIdx.x;
    int o = t >> 6;
    int c0 = (t & 63) << 3;
    double sa = 0.0, sv = 0.0;
#pragma unroll
    for (int i = 0; i < 64; ++i) {
        sa += part[(wid * 64 + i) * 2 + 0];
        sv += part[(wid * 64 + i) * 2 + 1];
    }
    float mf = (float)(sv * (1.0 / NW));
    float scf = fmaxf((float)(sa * (1.0 / NW)), 1e-8f);
    if ((blockIdx.x & 127) == 0 && threadIdx.x == 0) finals[wid] = (double)scf;

    const float sgn[4][4] = {{ 1.f, 1.f, 1.f, 1.f},
                             {-1.f, 1.f, 1.f,-1.f},
                             {-1.f,-1.f, 1.f, 1.f},
                             {-1.f, 1.f,-1.f, 1.f}};
    const float* wptr[4] = {w0, w1, w2, w3};
    const float* w = wptr[wid] + o * C + c0;
    float4v va = ((const float4v*)w)[0];
    float4v vb = ((const float4v*)w)[1];
    float q[8];
#pragma unroll
    for (int e = 0; e < 4; ++e) {
        q[e]     = rintf(fminf(fmaxf((va[e] - mf) / scf, -1.f), 1.f));
        q[4 + e] = rintf(fminf(fmaxf((vb[e] - mf) / scf, -1.f), 1.f));
    }
#pragma unroll
    for (int p = 0; p < 4; ++p) {
        int qb = p ^ wid;
        float s = sgn[wid][p];
        short8 v;
#pragma unroll
        for (int e = 0; e < 8; ++e) v[e] = (short)f2bf(s * q[e]);
        *(short8*)&Wb[(size_t)(p * C + o) * F + qb * C + c0] = v;
    }
}

// ---------------- Kernel 3 (fast): 256x256 single-phase-per-K-tile GEMM ----------------
// Per K-tile: {24 ds_read -> lgkmcnt(0) -> barrier -> stage ALL 8 gl_lds(t+2) ->
//  64-MFMA cluster (setprio) -> vmcnt(8) -> barrier}. 2 barriers/tile (was 8).
// Register-held operands: A 16 x b128, B 8 x b128. Swizzle c ^= (r&7)<<3 both sides.
__global__ __launch_bounds__(512, 2) void qb_gemm256(
    const unsigned short* __restrict__ A,   // Xb [M][2048]
    const unsigned short* __restrict__ B,   // Wb [2048][2048]
    const float* __restrict__ bias, const double* __restrict__ finals,
    float* __restrict__ out) {
    constexpr int K = F, N = F, BK = 64, NT = K / BK;   // NT = 32
    __shared__ unsigned short As[2][256 * 64];
    __shared__ unsigned short Bs[2][256 * 64];

    const int tid = threadIdx.x;
    const int lane = tid & 63;
    const int w = tid >> 6;           // 0..7
    const int wm = w >> 2, wn = w & 3;

    const int nbn = N / 256;          // 8
    const int nwg = gridDim.x;        // multiple of 8
    const int bid = blockIdx.x;
    const int swz = (bid & 7) * (nwg >> 3) + (bid >> 3);
    const int bm = swz / nbn, bn = swz % nbn;
    const int brow = bm * 256, bcol = bn * 256;

    const int frow = lane & 15;
    const int fk = (lane >> 4) << 3;

    // Precomputed stage slots: lds byte offset + global base ptr per (h,l) for A and B.
    int boff[2][2];
    const unsigned short* gpA[2][2];
    const unsigned short* gpB[2][2];
#pragma unroll
    for (int h = 0; h < 2; ++h)
#pragma unroll
        for (int l = 0; l < 2; ++l) {
            int bo = h * 16384 + (w * 2 + l) * 1024 + lane * 16;
            int e = bo >> 1;
            int r = e >> 6, c = e & 63;
            int csrc = c ^ ((r & 7) << 3);
            boff[h][l] = bo;
            gpA[h][l] = A + (size_t)(brow + r) * K + csrc;
            gpB[h][l] = B + (size_t)(bcol + r) * K + csrc;
        }

    auto stageAll = [&](int bufI, int kt) {
        int ko = (kt & (NT - 1)) * BK;
        char* la = (char*)&As[bufI][0];
        char* lb = (char*)&Bs[bufI][0];
#pragma unroll
        for (int h = 0; h < 2; ++h)
#pragma unroll
            for (int l = 0; l < 2; ++l) {
                __builtin_amdgcn_global_load_lds(
                    (const __attribute__((address_space(1))) void*)(gpA[h][l] + ko),
                    (__attribute__((address_space(3))) void*)(la + boff[h][l]), 16, 0, 0);
                __builtin_amdgcn_global_load_lds(
                    (const __attribute__((address_space(1))) void*)(gpB[h][l] + ko),
                    (__attribute__((address_space(3))) void*)(lb + boff[h][l]), 16, 0, 0);
            }
    };
    auto rdA = [&](int buf, int mh, int ks, int mi) -> short8 {
        int r = mh * 128 + wm * 64 + mi * 16 + frow;
        int cs = (ks * 32 + fk) ^ ((r & 7) << 3);
        return *(const short8*)&As[buf][r * 64 + cs];
    };
    auto rdB = [&](int buf, int nh, int ks, int ni) -> short8 {
        int r = nh * 128 + wn * 32 + ni * 16 + frow;
        int cs = (ks * 32 + fk) ^ ((r & 7) << 3);
        return *(const short8*)&Bs[buf][r * 64 + cs];
    };

    f32x4 acc[2][4][2][2];
#pragma unroll
    for (int a0 = 0; a0 < 2; ++a0)
#pragma unroll
        for (int a1 = 0; a1 < 4; ++a1)
#pragma unroll
            for (int a2 = 0; a2 < 2; ++a2)
#pragma unroll
                for (int a3 = 0; a3 < 2; ++a3) acc[a0][a1][a2][a3] = (f32x4){0.f, 0.f, 0.f, 0.f};

    // Prologue: stage tiles 0 and 1; vmcnt(8) => tile0 resident (tile1's 8 in flight).
    stageAll(0, 0);
    stageAll(1, 1);
    asm volatile("s_waitcnt vmcnt(8)" ::: "memory");
    __builtin_amdgcn_s_barrier();

    for (int t = 0; t < NT; ++t) {
        const int buf = t & 1;
        short8 a[2][4][2];   // [mh][mi][ks]
        short8 b[2][2][2];   // [nh][ni][ks]
#pragma unroll
        for (int mh = 0; mh < 2; ++mh)
#pragma unroll
            for (int mi = 0; mi < 4; ++mi)
#pragma unroll
                for (int ks = 0; ks < 2; ++ks) a[mh][mi][ks] = rdA(buf, mh, ks, mi);
#pragma unroll
        for (int nh = 0; nh < 2; ++nh)
#pragma unroll
            for (int ni = 0; ni < 2; ++ni)
#pragma unroll
                for (int ks = 0; ks < 2; ++ks) b[nh][ni][ks] = rdB(buf, nh, ks, ni);
        asm volatile("s_waitcnt lgkmcnt(0)" ::: "memory");   // reads landed in regs
        __builtin_amdgcn_sched_barrier(0);
        __builtin_amdgcn_s_barrier();                        // all waves done reading buf
        stageAll(buf, t + 2);                                // overwrite buf with t+2
        __builtin_amdgcn_s_setprio(1);
#pragma unroll
        for (int mh = 0; mh < 2; ++mh)
#pragma unroll
            for (int mi = 0; mi < 4; ++mi)
#pragma unroll
                for (int nh = 0; nh < 2; ++nh)
#pragma unroll
                    for (int ni = 0; ni < 2; ++ni)
#pragma unroll
                        for (int ks = 0; ks < 2; ++ks)
                            acc[mh][mi][nh][ni] = __builtin_amdgcn_mfma_f32_16x16x32_bf16(
                                a[mh][mi][ks], b[nh][ni][ks], acc[mh][mi][nh][ni], 0, 0, 0);
        __builtin_amdgcn_s_setprio(0);
        asm volatile("s_waitcnt vmcnt(8)" ::: "memory");     // t+1's loads retired
        __builtin_amdgcn_s_barrier();                        // ... for ALL waves
    }

    float mul = (float)((finals[0] + finals[1] + finals[2] + finals[3]) * (0.25 * 0.5));

#pragma unroll
    for (int mh = 0; mh < 2; ++mh)
#pragma unroll
        for (int nh = 0; nh < 2; ++nh)
#pragma unroll
            for (int ni = 0; ni < 2; ++ni) {
                int gcol = bcol + nh * 128 + wn * 32 + ni * 16 + frow;
                float bv = bias[gcol];
#pragma unroll
                for (int mi = 0; mi < 4; ++mi) {
                    int gr0 = brow + mh * 128 + wm * 64 + mi * 16 + ((lane >> 4) << 2);
#pragma unroll
                    for (int j = 0; j < 4; ++j)
                        out[(size_t)(gr0 + j) * N + gcol] = (acc[mh][mi][nh][ni][j] + bv) * mul;
                }
            }
}

// ---------------- Kernel 3 (fallback): 128x128 GEMM, fp32 X in-loop convert ----------------
__global__ __launch_bounds__(256) void qb_gemm(
    const float* __restrict__ X, const unsigned short* __restrict__ Wb,
    const float* __restrict__ bias, const double* __restrict__ finals,
    float* __restrict__ out, int M) {
    constexpr int Kd = F, Nd = F;
    __shared__ unsigned short As[128 * 32];
    __shared__ unsigned short Bs[128 * 32];
    const int t = threadIdx.x;
    const int lane = t & 63, wv = t >> 6;
    const int nbn = Nd / 128;
    const int nwg = gridDim.x;
    const int bid = blockIdx.x;
    const int swz = (bid & 7) * (nwg >> 3) + (bid >> 3);
    const int bm = swz / nbn, bn = swz % nbn;
    const int brow = bm * 128, bcol = bn * 128;
    const int wr = wv >> 1, wc = wv & 1;
    const int frow = lane & 15;
    const int k8 = (lane >> 4) << 3;
    f32x4 acc[4][4];
#pragma unroll
    for (int i = 0; i < 4; ++i)
#pragma unroll
        for (int j = 0; j < 4; ++j) acc[i][j] = (f32x4){0.f, 0.f, 0.f, 0.f};
    const int ar = t >> 3;
    const int ac = (t & 7) << 2;
    for (int kk = 0; kk < Kd; kk += 32) {
#pragma unroll
        for (int is = 0; is < 2; ++is) {
            int idx = is * 2048 + t * 8;
            int row = idx >> 5, col = idx & 31;
            const unsigned short* src = &Wb[(size_t)(bcol + row) * Kd + kk + col];
            __builtin_amdgcn_global_load_lds(
                (const __attribute__((address_space(1))) void*)src,
                (__attribute__((address_space(3))) void*)&Bs[idx], 16, 0, 0);
        }
#pragma unroll
        for (int it = 0; it < 4; ++it) {
            int row = it * 32 + ar;
            float4v v = *(const float4v*)&X[(size_t)(brow + row) * Kd + kk + ac];
            ushort4v h;
            h[0] = f2bf(v[0]); h[1] = f2bf(v[1]); h[2] = f2bf(v[2]); h[3] = f2bf(v[3]);
            *(ushort4v*)&As[row * 32 + ac] = h;
        }
        __syncthreads();
        short8 a[4], b[4];
#pragma unroll
        for (int mi = 0; mi < 4; ++mi)
            a[mi] = *(const short8*)&As[(wr * 64 + mi * 16 + frow) * 32 + k8];
#pragma unroll
        for (int ni = 0; ni < 4; ++ni)
            b[ni] = *(const short8*)&Bs[(wc * 64 + ni * 16 + frow) * 32 + k8];
#pragma unroll
        for (int mi = 0; mi < 4; ++mi)
#pragma unroll
            for (int ni = 0; ni < 4; ++ni)
                acc[mi][ni] = __builtin_amdgcn_mfma_f32_16x16x32_bf16(
                    a[mi], b[ni], acc[mi][ni], 0, 0, 0);
        __syncthreads();
    }
    float mul = (float)((finals[0] + finals[1] + finals[2] + finals[3]) * (0.25 * 0.5));
#pragma unroll
    for (int ni = 0; ni < 4; ++ni) {
        int gcol = bcol + wc * 64 + ni * 16 + frow;
        float bv = bias[gcol];
#pragma unroll
        for (int mi = 0; mi < 4; ++mi) {
            int growb = brow + wr * 64 + mi * 16 + ((lane >> 4) << 2);
#pragma unroll
            for (int j = 0; j < 4; ++j)
                out[(size_t)(growb + j) * Nd + gcol] = (acc[mi][ni][j] + bv) * mul;
        }
    }
}

extern "C" void kernel_launch(void* const* d_in, const int* in_sizes, int n_in,
                              void* d_out, int out_size, void* d_ws, size_t ws_size,
                              hipStream_t stream) {
    const float* x    = (const float*)d_in[0];
    const float* wr_  = (const float*)d_in[1];
    const float* wi_  = (const float*)d_in[2];
    const float* wj_  = (const float*)d_in[3];
    const float* wk_  = (const float*)d_in[4];
    const float* bias = (const float*)d_in[5];
    float* out = (float*)d_out;
    const int M = in_sizes[0] / F;   // 16384

    const size_t FIN_OFF = 4096;                               // part: [0,4096)
    const size_t WB_OFF  = 8192;
    const size_t XB_OFF  = WB_OFF + (size_t)F * F * 2;         // + 8 MiB
    const size_t NEED    = XB_OFF + (size_t)M * F * 2;         // + 64 MiB

    double* part   = (double*)d_ws;
    double* finals = (double*)((char*)d_ws + FIN_OFF);
    unsigned short* Wb = (unsigned short*)((char*)d_ws + WB_OFF);
    unsigned short* Xb = (unsigned short*)((char*)d_ws + XB_OFF);

    const bool fast = (ws_size >= NEED) && (M % 256) == 0;

    qb_prep<<<2304, 256, 0, stream>>>(x, Xb, fast ? (M * F) / 8 : 0,
                                      wr_, wi_, wj_, wk_, part);
    qb_build<<<512, 256, 0, stream>>>(wr_, wi_, wj_, wk_, part, Wb, finals);

    if (fast) {
        const int grid = (M / 256) * (F / 256);                // 512, %8==0
        qb_gemm256<<<grid, 512, 0, stream>>>(Xb, Wb, bias, finals, out);
    } else {
        const int grid = (M / 128) * (F / 128);
        qb_gemm<<<grid, 256, 0, stream>>>(x, Wb, bias, finals, out, M);
    }
}